// Round 1
// baseline (597.593 us; speedup 1.0000x reference)
//
#include <hip/hip_runtime.h>
#include <math.h>

#define H      128
#define LNUM   5
#define ONUM   5
#define BATCH  16
#define NPTS   50000
#define TP     128      // points per trunk block
#define XROW   136      // ushorts per xs row: 128 + 8 pad (272 B, 16B-aligned, 68 words ≡ 4 mod 32)
#define WROW   72       // ushorts per W-chunk row: 64 + 8 pad (144 B)

typedef __bf16  bf16x8   __attribute__((ext_vector_type(8)));
typedef float   floatx4  __attribute__((ext_vector_type(4)));
typedef unsigned short ushort8_t __attribute__((ext_vector_type(8)));

static __device__ __forceinline__ unsigned short f2bf(float f) {
    unsigned int u = __builtin_bit_cast(unsigned int, f);
    u += 0x7fffu + ((u >> 16) & 1u);          // round-to-nearest-even
    return (unsigned short)(u >> 16);
}

static __device__ __forceinline__ float fast_tanh(float x) {
    // tanh(x) = 1 - 2/(e^{2x}+1); v_exp_f32-based, saturates correctly at +-inf
    float e = __expf(2.0f * x);
    return 1.0f - 2.0f / (e + 1.0f);
}

// ---------------- prep: transpose+cast trunk weights to bf16 Wt[t][k] ----------------
__global__ void prep_wt(const float* __restrict__ tWh, const float* __restrict__ tWf,
                        unsigned short* __restrict__ wt) {
    int m = blockIdx.x;                                  // 0..3 = Wh[m], 4 = Wf
    const float* src = (m < 4) ? (tWh + m * H * H) : tWf;
    unsigned short* dst = wt + m * H * H;
    for (int i = threadIdx.x; i < H * H; i += blockDim.x) {
        int t = i >> 7, k = i & 127;                     // dst[t][k] = src[k][t]
        dst[i] = f2bf(src[k * H + t]);
    }
}

// ---------------- branch MLP: one block per batch ----------------
__global__ void branch_kernel(const float* __restrict__ params,
                              const float* __restrict__ bW0, const float* __restrict__ bb0,
                              const float* __restrict__ bWh, const float* __restrict__ bbh,
                              const float* __restrict__ balpha,
                              const float* __restrict__ bWf, const float* __restrict__ bbf,
                              float* __restrict__ Sws, unsigned short* __restrict__ ZLws) {
    int b = blockIdx.x, t = threadIdx.x;                 // 128 threads
    __shared__ float hbuf[H];
    __shared__ float pbuf[8];
    if (t < 8) pbuf[t] = params[b * 8 + t];
    __syncthreads();

    float acc = bb0[t];
    for (int k = 0; k < 8; ++k) acc += pbuf[k] * bW0[k * H + t];
    float h = balpha[t] * tanhf(acc);
    float scum = h;
    hbuf[t] = h;
    Sws[(b * LNUM + 0) * H + t] = scum;

    for (int i = 1; i < LNUM; ++i) {
        __syncthreads();
        const float* Wl = bWh + (i - 1) * H * H;
        float a2 = bbh[(i - 1) * H + t];
        for (int k = 0; k < H; ++k) a2 += hbuf[k] * Wl[k * H + t];
        float hn = balpha[i * H + t] * tanhf(a2);
        __syncthreads();
        hbuf[t] = hn;
        scum += hn;
        Sws[(b * LNUM + i) * H + t] = scum;
    }
    __syncthreads();
    // ZL[b][o][h] = h4 @ Wf[:, o*H+h] + bf ; rows o=5..15 zero-padded for MFMA
    for (int o = 0; o < 16; ++o) {
        float z = 0.0f;
        if (o < ONUM) {
            z = bbf[o * H + t];
            for (int k = 0; k < H; ++k) z += hbuf[k] * bWf[k * (H * ONUM) + o * H + t];
        }
        ZLws[(b * 16 + o) * H + t] = f2bf(z);
    }
}

// ---------------- trunk: 128 points/block, bf16 MFMA ----------------
__global__ __launch_bounds__(256, 2)
void trunk_kernel(const float* __restrict__ coords,
                  const float* __restrict__ tW0, const float* __restrict__ tb0,
                  const float* __restrict__ tbh, const float* __restrict__ talpha,
                  const float* __restrict__ tbf,
                  const unsigned short* __restrict__ wt,
                  const float* __restrict__ Sws, const unsigned short* __restrict__ ZLws,
                  float* __restrict__ out) {
    const int b   = blockIdx.y;
    const int n0  = blockIdx.x * TP;
    const int tid = threadIdx.x;
    const int lane = tid & 63;
    const int w    = tid >> 6;        // wave 0..3 -> points [32w, 32w+32)
    const int q    = lane >> 4;       // quad 0..3
    const int c    = lane & 15;

    __shared__ unsigned short xs[TP * XROW];   // activations, bf16 [point][k]
    __shared__ unsigned short wb[H * WROW];    // W chunk, bf16 [t][k_local]
    __shared__ float cs[TP * 3];

    // ---- stage coords ----
    int valid = NPTS - n0; if (valid > TP) valid = TP;
    for (int i = tid; i < TP * 3; i += 256) {
        float v = 0.0f;
        if (i < valid * 3) v = coords[(size_t)(b * NPTS + n0) * 3 + i];
        cs[i] = v;
    }
    __syncthreads();

    // ---- layer 0: x = alpha0 * tanh((coords@W0 + b0) * S0) ----
    {
        int t  = tid & 127;
        int ph = (tid >> 7) * 64;
        float w0 = tW0[t], w1 = tW0[H + t], w2 = tW0[2 * H + t];
        float bb = tb0[t];
        float al = talpha[t];
        float Sv = Sws[(b * LNUM + 0) * H + t];
        for (int p = ph; p < ph + 64; ++p) {
            float v = cs[p * 3] * w0 + cs[p * 3 + 1] * w1 + cs[p * 3 + 2] * w2 + bb;
            xs[p * XROW + t] = f2bf(al * fast_tanh(v * Sv));
        }
    }

    const int mrow0 = w * 32 + c;     // A-frag row (m) for mt=0; mt=1 adds +16

    // ---- layers 1..4 (Wh) and 5 (Wf) ----
    for (int layer = 1; layer <= 5; ++layer) {
        const unsigned short* wsrc = wt + (layer - 1) * H * H;
        floatx4 acc[2][8];
        #pragma unroll
        for (int mt = 0; mt < 2; ++mt)
            #pragma unroll
            for (int nt = 0; nt < 8; ++nt)
                acc[mt][nt] = (floatx4){0.0f, 0.0f, 0.0f, 0.0f};

        #pragma unroll
        for (int chunk = 0; chunk < 2; ++chunk) {
            __syncthreads();                          // xs ready / prev wb use done
            // stage W chunk: k in [chunk*64, chunk*64+64)
            #pragma unroll
            for (int it = 0; it < 4; ++it) {
                int idx = tid + it * 256;             // 1024 ushort8 chunks
                int row = idx >> 3, jj = (idx & 7) * 8;
                *(ushort8_t*)(&wb[row * WROW + jj]) =
                    *(const ushort8_t*)(&wsrc[row * H + chunk * 64 + jj]);
            }
            __syncthreads();

            #pragma unroll
            for (int shalf = 0; shalf < 2; ++shalf) {
                int s = chunk * 2 + shalf;            // k-step 0..3 (k = 32s)
                bf16x8 afr[2];
                #pragma unroll
                for (int mt = 0; mt < 2; ++mt) {
                    const unsigned short* p = &xs[(mrow0 + mt * 16) * XROW + s * 32 + q * 8];
                    afr[mt] = __builtin_bit_cast(bf16x8, *(const ushort8_t*)p);
                }
                #pragma unroll
                for (int nt = 0; nt < 8; ++nt) {
                    const unsigned short* p = &wb[(nt * 16 + c) * WROW + shalf * 32 + q * 8];
                    bf16x8 bfr = __builtin_bit_cast(bf16x8, *(const ushort8_t*)p);
                    acc[0][nt] = __builtin_amdgcn_mfma_f32_16x16x32_bf16(afr[0], bfr, acc[0][nt], 0, 0, 0);
                    acc[1][nt] = __builtin_amdgcn_mfma_f32_16x16x32_bf16(afr[1], bfr, acc[1][nt], 0, 0, 0);
                }
            }
        }
        __syncthreads();                              // all xs reads done before overwrite

        if (layer < 5) {
            const float* Sl = &Sws[(b * LNUM + layer) * H];
            const float* bh = &tbh[(layer - 1) * H];
            const float* al = &talpha[layer * H];
            #pragma unroll
            for (int nt = 0; nt < 8; ++nt) {
                int t = nt * 16 + c;
                float bv = bh[t], av = al[t], Sv = Sl[t];
                #pragma unroll
                for (int mt = 0; mt < 2; ++mt) {
                    int prow = w * 32 + mt * 16 + q * 4;
                    #pragma unroll
                    for (int r = 0; r < 4; ++r) {
                        float v = acc[mt][nt][r] + bv;
                        xs[(prow + r) * XROW + t] = f2bf(av * fast_tanh(v * Sv));
                    }
                }
            }
        } else {
            // final: YL = x@Wf + bf (no activation)
            #pragma unroll
            for (int nt = 0; nt < 8; ++nt) {
                int t = nt * 16 + c;
                float bv = tbf[t];
                #pragma unroll
                for (int mt = 0; mt < 2; ++mt) {
                    int prow = w * 32 + mt * 16 + q * 4;
                    #pragma unroll
                    for (int r = 0; r < 4; ++r)
                        xs[(prow + r) * XROW + t] = f2bf(acc[mt][nt][r] + bv);
                }
            }
        }
    }
    __syncthreads();                                  // YL in xs ready

    // ---- einsum: out[b,n,o] = sum_h YL[n,h] * ZL[b,o,h] ----
    {
        floatx4 oacc[2] = {(floatx4){0,0,0,0}, (floatx4){0,0,0,0}};
        const unsigned short* zl = &ZLws[b * 16 * H];
        #pragma unroll
        for (int s = 0; s < 4; ++s) {
            bf16x8 bfr = __builtin_bit_cast(bf16x8,
                *(const ushort8_t*)&zl[c * H + s * 32 + q * 8]);
            #pragma unroll
            for (int mt = 0; mt < 2; ++mt) {
                const unsigned short* p = &xs[(mrow0 + mt * 16) * XROW + s * 32 + q * 8];
                bf16x8 afr = __builtin_bit_cast(bf16x8, *(const ushort8_t*)p);
                oacc[mt] = __builtin_amdgcn_mfma_f32_16x16x32_bf16(afr, bfr, oacc[mt], 0, 0, 0);
            }
        }
        if (c < ONUM) {
            #pragma unroll
            for (int mt = 0; mt < 2; ++mt) {
                int prow = w * 32 + mt * 16 + q * 4;
                #pragma unroll
                for (int r = 0; r < 4; ++r) {
                    int p = prow + r;
                    if (n0 + p < NPTS)
                        out[((size_t)b * NPTS + n0 + p) * ONUM + c] = oacc[mt][r];
                }
            }
        }
    }
}

extern "C" void kernel_launch(void* const* d_in, const int* in_sizes, int n_in,
                              void* d_out, int out_size, void* d_ws, size_t ws_size,
                              hipStream_t stream) {
    const float* coords       = (const float*)d_in[0];
    const float* params       = (const float*)d_in[1];
    const float* branch_W0    = (const float*)d_in[2];
    const float* branch_b0    = (const float*)d_in[3];
    const float* branch_Wh    = (const float*)d_in[4];
    const float* branch_bh    = (const float*)d_in[5];
    const float* branch_alpha = (const float*)d_in[6];
    const float* branch_Wf    = (const float*)d_in[7];
    const float* branch_bf    = (const float*)d_in[8];
    const float* trunk_W0     = (const float*)d_in[9];
    const float* trunk_b0     = (const float*)d_in[10];
    const float* trunk_Wh     = (const float*)d_in[11];
    const float* trunk_bh     = (const float*)d_in[12];
    const float* trunk_alpha  = (const float*)d_in[13];
    const float* trunk_Wf     = (const float*)d_in[14];
    const float* trunk_bf     = (const float*)d_in[15];
    float* out = (float*)d_out;

    // workspace layout
    char* ws = (char*)d_ws;
    float*          Sws  = (float*)(ws + 0);                    // 16*5*128 f32   = 40960 B
    unsigned short* ZLws = (unsigned short*)(ws + 40960);       // 16*16*128 bf16 = 65536 B
    unsigned short* wt   = (unsigned short*)(ws + 106496);      // 5*128*128 bf16 = 163840 B

    prep_wt<<<dim3(5), 256, 0, stream>>>(trunk_Wh, trunk_Wf, wt);
    branch_kernel<<<dim3(BATCH), 128, 0, stream>>>(params, branch_W0, branch_b0,
                                                   branch_Wh, branch_bh, branch_alpha,
                                                   branch_Wf, branch_bf, Sws, ZLws);
    trunk_kernel<<<dim3((NPTS + TP - 1) / TP, BATCH), 256, 0, stream>>>(
        coords, trunk_W0, trunk_b0, trunk_bh, trunk_alpha, trunk_bf,
        wt, Sws, ZLws, out);
}

// Round 2
// 442.040 us; speedup vs baseline: 1.3519x; 1.3519x over previous
//
#include <hip/hip_runtime.h>
#include <math.h>

#define H      128
#define LNUM   5
#define ONUM   5
#define BATCH  16
#define NPTS   50000
#define TP     128      // points per trunk block
#define XROW   136      // halfs per xs row: 128 + 8 pad (272 B, 16B-aligned)

#define K2LOG2E 2.8853900817779268f   // 2*log2(e): tanh arg -> exp2 arg

typedef _Float16      half8    __attribute__((ext_vector_type(8)));
typedef _Float16      half2v   __attribute__((ext_vector_type(2)));
typedef float         floatx4  __attribute__((ext_vector_type(4)));
typedef unsigned int  uint2v   __attribute__((ext_vector_type(2)));
typedef unsigned int  uint4v   __attribute__((ext_vector_type(4)));
typedef unsigned short ushort8_t __attribute__((ext_vector_type(8)));

static __device__ __forceinline__ unsigned short f2h(float f) {
    _Float16 h = (_Float16)f;                       // v_cvt_f16_f32 (RNE)
    return __builtin_bit_cast(unsigned short, h);
}

// tanh epilogue core: out = a * tanh(v*S + bias), with sp=2log2e*S, bp=sp*bias
static __device__ __forceinline__ float rowdy(float v, float sp, float bp, float a) {
    float t  = v * sp + bp;                          // v_fma
    float e  = __builtin_amdgcn_exp2f(t);            // v_exp_f32: e = 2^t = exp(2*(vS+b))
    float rc = __builtin_amdgcn_rcpf(e + 1.0f);      // v_rcp_f32
    return a * (1.0f - 2.0f * rc);                   // fma + mul ; saturates to +-a
}

// ---------------- prep: transpose+cast trunk weights to fp16 ----------------
__global__ void prep_wt(const float* __restrict__ tWh, const float* __restrict__ tWf,
                        const float* __restrict__ tW0,
                        unsigned short* __restrict__ wt, unsigned short* __restrict__ w0t) {
    int m = blockIdx.x;                              // 0..3 = Wh[m], 4 = Wf, 5 = W0(padded)
    if (m < 5) {
        const float* src = (m < 4) ? (tWh + m * H * H) : tWf;
        unsigned short* dst = wt + m * H * H;
        for (int i = threadIdx.x; i < H * H; i += blockDim.x) {
            int t = i >> 7, k = i & 127;             // dst[t][k] = src[k][t]
            dst[i] = f2h(src[k * H + t]);
        }
    } else {
        for (int i = threadIdx.x; i < H * 32; i += blockDim.x) {
            int t = i >> 5, k = i & 31;              // w0t[t][k] = W0[k][t], k>=3 zero
            w0t[i] = (k < 3) ? f2h(tW0[k * H + t]) : 0;
        }
    }
}

// ---------------- branch MLP + FiLM-constant precompute: one block per batch ----------------
__global__ void branch_kernel(const float* __restrict__ params,
                              const float* __restrict__ bW0, const float* __restrict__ bb0,
                              const float* __restrict__ bWh, const float* __restrict__ bbh,
                              const float* __restrict__ balpha,
                              const float* __restrict__ bWf, const float* __restrict__ bbf,
                              const float* __restrict__ tb0, const float* __restrict__ tbh,
                              float* __restrict__ SPP, float* __restrict__ BPP,
                              unsigned short* __restrict__ ZLws) {
    int b = blockIdx.x, t = threadIdx.x;             // 128 threads
    __shared__ float hbuf[H];
    __shared__ float pbuf[8];
    if (t < 8) pbuf[t] = params[b * 8 + t];
    __syncthreads();

    float acc = bb0[t];
    for (int k = 0; k < 8; ++k) acc += pbuf[k] * bW0[k * H + t];
    float h = balpha[t] * tanhf(acc);
    float scum = h;
    hbuf[t] = h;
    {
        float sp = K2LOG2E * scum;
        SPP[(b * LNUM + 0) * H + t] = sp;
        BPP[(b * LNUM + 0) * H + t] = sp * tb0[t];
    }

    for (int i = 1; i < LNUM; ++i) {
        __syncthreads();
        const float* Wl = bWh + (i - 1) * H * H;
        float a2 = bbh[(i - 1) * H + t];
        for (int k = 0; k < H; ++k) a2 += hbuf[k] * Wl[k * H + t];
        float hn = balpha[i * H + t] * tanhf(a2);
        __syncthreads();
        hbuf[t] = hn;
        scum += hn;
        float sp = K2LOG2E * scum;
        SPP[(b * LNUM + i) * H + t] = sp;
        BPP[(b * LNUM + i) * H + t] = sp * tbh[(i - 1) * H + t];
    }
    __syncthreads();
    // ZL[b][o][h]; rows o=5..15 zero-padded (those D rows are discarded anyway)
    for (int o = 0; o < 16; ++o) {
        float z = 0.0f;
        if (o < ONUM) {
            z = bbf[o * H + t];
            for (int k = 0; k < H; ++k) z += hbuf[k] * bWf[k * (H * ONUM) + o * H + t];
        }
        ZLws[(b * 16 + o) * H + t] = f2h(z);
    }
}

// ---------------- trunk: 128 points/block, fp16 MFMA, feature-major D ----------------
__global__ __launch_bounds__(256, 3)
void trunk_kernel(const float* __restrict__ coords,
                  const float* __restrict__ talpha, const float* __restrict__ tbf,
                  const unsigned short* __restrict__ wt,
                  const unsigned short* __restrict__ w0t,
                  const float* __restrict__ SPP, const float* __restrict__ BPP,
                  const unsigned short* __restrict__ ZLws,
                  float* __restrict__ out) {
    const int b    = blockIdx.y;
    const int n0   = blockIdx.x * TP;
    const int tid  = threadIdx.x;
    const int lane = tid & 63;
    const int w    = tid >> 6;
    const int q    = lane >> 4;       // quad 0..3
    const int c    = lane & 15;
    const int mh   = (w & 1) * 64;    // wave's feature half (MFMA M)
    const int nh   = (w >> 1) * 64;   // wave's point half   (MFMA N)

    __shared__ unsigned short xs[TP * XROW];   // activations fp16, [point][feat]

    // ---- stage coords into xs[p][0..31] (fp16, zero-padded K) ----
    int valid = NPTS - n0; if (valid > TP) valid = TP;
    {
        int p = tid >> 1, hh = tid & 1;
        uint4v z = {0, 0, 0, 0};
        if (hh == 0) {
            float c0 = 0.f, c1 = 0.f, c2 = 0.f;
            if (p < valid) {
                const float* cp = coords + ((size_t)b * NPTS + n0 + p) * 3;
                c0 = cp[0]; c1 = cp[1]; c2 = cp[2];
            }
            z.x = __builtin_bit_cast(unsigned int, __builtin_amdgcn_cvt_pkrtz(c0, c1));
            z.y = __builtin_bit_cast(unsigned int, __builtin_amdgcn_cvt_pkrtz(c2, 0.0f));
            *(uint4v*)&xs[p * XROW + 0] = z;                 // k 0..7
            uint4v zz = {0, 0, 0, 0};
            *(uint4v*)&xs[p * XROW + 8] = zz;                // k 8..15
        } else {
            *(uint4v*)&xs[p * XROW + 16] = z;                // k 16..31
            *(uint4v*)&xs[p * XROW + 24] = z;
        }
    }

    floatx4 acc[4][4];

    // ================= layer 0: coords(K=32 padded) =================
    #pragma unroll
    for (int mt = 0; mt < 4; ++mt)
        #pragma unroll
        for (int nt = 0; nt < 4; ++nt)
            acc[mt][nt] = (floatx4){0.f, 0.f, 0.f, 0.f};
    __syncthreads();
    {
        half8 af[4], bfr[4];
        #pragma unroll
        for (int mt = 0; mt < 4; ++mt)
            af[mt] = __builtin_bit_cast(half8,
                *(const ushort8_t*)&w0t[(mh + mt * 16 + c) * 32 + q * 8]);
        #pragma unroll
        for (int nt = 0; nt < 4; ++nt)
            bfr[nt] = __builtin_bit_cast(half8,
                *(const ushort8_t*)&xs[(nh + nt * 16 + c) * XROW + q * 8]);
        #pragma unroll
        for (int mt = 0; mt < 4; ++mt)
            #pragma unroll
            for (int nt = 0; nt < 4; ++nt)
                acc[mt][nt] = __builtin_amdgcn_mfma_f32_16x16x32_f16(af[mt], bfr[nt], acc[mt][nt], 0, 0, 0);
    }
    __syncthreads();
    // epilogue layer 0
    #pragma unroll
    for (int mt = 0; mt < 4; ++mt) {
        int f0 = mh + mt * 16 + q * 4;
        floatx4 s4 = *(const floatx4*)&SPP[(b * LNUM + 0) * H + f0];
        floatx4 b4 = *(const floatx4*)&BPP[(b * LNUM + 0) * H + f0];
        floatx4 a4 = *(const floatx4*)&talpha[0 * H + f0];
        #pragma unroll
        for (int nt = 0; nt < 4; ++nt) {
            int pt = nh + nt * 16 + c;
            floatx4 v = acc[mt][nt];
            #pragma unroll
            for (int r = 0; r < 4; ++r) v[r] = rowdy(v[r], s4[r], b4[r], a4[r]);
            uint2v u;
            u.x = __builtin_bit_cast(unsigned int, __builtin_amdgcn_cvt_pkrtz(v[0], v[1]));
            u.y = __builtin_bit_cast(unsigned int, __builtin_amdgcn_cvt_pkrtz(v[2], v[3]));
            *(uint2v*)&xs[pt * XROW + f0] = u;
        }
    }

    // ================= hidden layers 1..4 and final layer 5 =================
    for (int l = 1; l <= 5; ++l) {
        const unsigned short* wl = wt + (l - 1) * H * H;
        #pragma unroll
        for (int mt = 0; mt < 4; ++mt)
            #pragma unroll
            for (int nt = 0; nt < 4; ++nt)
                acc[mt][nt] = (floatx4){0.f, 0.f, 0.f, 0.f};
        __syncthreads();                              // prev epilogue writes visible
        #pragma unroll
        for (int s = 0; s < 4; ++s) {
            half8 af[4], bfr[4];
            #pragma unroll
            for (int mt = 0; mt < 4; ++mt)
                af[mt] = __builtin_bit_cast(half8,
                    *(const ushort8_t*)&wl[(mh + mt * 16 + c) * H + s * 32 + q * 8]);
            #pragma unroll
            for (int nt = 0; nt < 4; ++nt)
                bfr[nt] = __builtin_bit_cast(half8,
                    *(const ushort8_t*)&xs[(nh + nt * 16 + c) * XROW + s * 32 + q * 8]);
            #pragma unroll
            for (int mt = 0; mt < 4; ++mt)
                #pragma unroll
                for (int nt = 0; nt < 4; ++nt)
                    acc[mt][nt] = __builtin_amdgcn_mfma_f32_16x16x32_f16(af[mt], bfr[nt], acc[mt][nt], 0, 0, 0);
        }
        __syncthreads();                              // all xs reads done

        if (l < 5) {
            #pragma unroll
            for (int mt = 0; mt < 4; ++mt) {
                int f0 = mh + mt * 16 + q * 4;
                floatx4 s4 = *(const floatx4*)&SPP[(b * LNUM + l) * H + f0];
                floatx4 b4 = *(const floatx4*)&BPP[(b * LNUM + l) * H + f0];
                floatx4 a4 = *(const floatx4*)&talpha[l * H + f0];
                #pragma unroll
                for (int nt = 0; nt < 4; ++nt) {
                    int pt = nh + nt * 16 + c;
                    floatx4 v = acc[mt][nt];
                    #pragma unroll
                    for (int r = 0; r < 4; ++r) v[r] = rowdy(v[r], s4[r], b4[r], a4[r]);
                    uint2v u;
                    u.x = __builtin_bit_cast(unsigned int, __builtin_amdgcn_cvt_pkrtz(v[0], v[1]));
                    u.y = __builtin_bit_cast(unsigned int, __builtin_amdgcn_cvt_pkrtz(v[2], v[3]));
                    *(uint2v*)&xs[pt * XROW + f0] = u;
                }
            }
        } else {
            // YL = x@Wf + bf (no activation)
            #pragma unroll
            for (int mt = 0; mt < 4; ++mt) {
                int f0 = mh + mt * 16 + q * 4;
                floatx4 f4 = *(const floatx4*)&tbf[f0];
                #pragma unroll
                for (int nt = 0; nt < 4; ++nt) {
                    int pt = nh + nt * 16 + c;
                    floatx4 v = acc[mt][nt];
                    uint2v u;
                    u.x = __builtin_bit_cast(unsigned int, __builtin_amdgcn_cvt_pkrtz(v[0] + f4[0], v[1] + f4[1]));
                    u.y = __builtin_bit_cast(unsigned int, __builtin_amdgcn_cvt_pkrtz(v[2] + f4[2], v[3] + f4[3]));
                    *(uint2v*)&xs[pt * XROW + f0] = u;
                }
            }
        }
    }
    __syncthreads();                                  // YL ready in xs

    // ---- einsum: out[b,pt,o] = sum_h ZL[o,h] * YL[pt,h]; A=ZL (m=o), B=YL (n=pt) ----
    {
        floatx4 oacc[2] = {(floatx4){0,0,0,0}, (floatx4){0,0,0,0}};
        const unsigned short* zl = ZLws + b * 16 * H;
        #pragma unroll
        for (int s = 0; s < 4; ++s) {
            half8 af = __builtin_bit_cast(half8,
                *(const ushort8_t*)&zl[c * H + s * 32 + q * 8]);
            #pragma unroll
            for (int nt = 0; nt < 2; ++nt) {
                half8 bfr = __builtin_bit_cast(half8,
                    *(const ushort8_t*)&xs[(w * 32 + nt * 16 + c) * XROW + s * 32 + q * 8]);
                oacc[nt] = __builtin_amdgcn_mfma_f32_16x16x32_f16(af, bfr, oacc[nt], 0, 0, 0);
            }
        }
        #pragma unroll
        for (int nt = 0; nt < 2; ++nt) {
            int pt = n0 + w * 32 + nt * 16 + c;
            if (pt < NPTS) {
                float* op = out + ((size_t)b * NPTS + pt) * ONUM;
                if (q == 0) {
                    op[0] = oacc[nt][0]; op[1] = oacc[nt][1];
                    op[2] = oacc[nt][2]; op[3] = oacc[nt][3];
                } else if (q == 1) {
                    op[4] = oacc[nt][0];
                }
            }
        }
    }
}

extern "C" void kernel_launch(void* const* d_in, const int* in_sizes, int n_in,
                              void* d_out, int out_size, void* d_ws, size_t ws_size,
                              hipStream_t stream) {
    const float* coords       = (const float*)d_in[0];
    const float* params       = (const float*)d_in[1];
    const float* branch_W0    = (const float*)d_in[2];
    const float* branch_b0    = (const float*)d_in[3];
    const float* branch_Wh    = (const float*)d_in[4];
    const float* branch_bh    = (const float*)d_in[5];
    const float* branch_alpha = (const float*)d_in[6];
    const float* branch_Wf    = (const float*)d_in[7];
    const float* branch_bf    = (const float*)d_in[8];
    const float* trunk_W0     = (const float*)d_in[9];
    const float* trunk_b0     = (const float*)d_in[10];
    const float* trunk_Wh     = (const float*)d_in[11];
    const float* trunk_bh     = (const float*)d_in[12];
    const float* trunk_alpha  = (const float*)d_in[13];
    const float* trunk_Wf     = (const float*)d_in[14];
    const float* trunk_bf     = (const float*)d_in[15];
    float* out = (float*)d_out;

    // workspace layout (all 256B-aligned)
    char* ws = (char*)d_ws;
    float*          SPP  = (float*)(ws + 0);                 // 16*5*128 f32  = 40960
    float*          BPP  = (float*)(ws + 40960);             // 16*5*128 f32  = 40960
    unsigned short* ZLws = (unsigned short*)(ws + 81920);    // 16*16*128 f16 = 65536
    unsigned short* wt   = (unsigned short*)(ws + 147456);   // 5*128*128 f16 = 163840
    unsigned short* w0t  = (unsigned short*)(ws + 311296);   // 128*32 f16    = 8192

    prep_wt<<<dim3(6), 256, 0, stream>>>(trunk_Wh, trunk_Wf, trunk_W0, wt, w0t);
    branch_kernel<<<dim3(BATCH), 128, 0, stream>>>(params, branch_W0, branch_b0,
                                                   branch_Wh, branch_bh, branch_alpha,
                                                   branch_Wf, branch_bf,
                                                   trunk_b0, trunk_bh,
                                                   SPP, BPP, ZLws);
    trunk_kernel<<<dim3((NPTS + TP - 1) / TP, BATCH), 256, 0, stream>>>(
        coords, trunk_alpha, trunk_bf, wt, w0t, SPP, BPP, ZLws, out);
}